// Round 6
// baseline (350.902 us; speedup 1.0000x reference)
//
#include <hip/hip_runtime.h>

typedef float f32x4 __attribute__((ext_vector_type(4)));
typedef __bf16 bf16x8 __attribute__((ext_vector_type(8)));
typedef unsigned short u16x8 __attribute__((ext_vector_type(8)));
typedef unsigned int u32x4 __attribute__((ext_vector_type(4)));

#define NBH 16
#define NSEQ 4096
#define DH 64

__device__ __forceinline__ unsigned int cvtpk(float lo, float hi) {
  unsigned int r;
  asm("v_cvt_pk_bf16_f32 %0, %1, %2" : "=v"(r) : "v"(lo), "v"(hi));
  return r;
}
__device__ __forceinline__ bf16x8 pk8(const float* f) {
  union { unsigned int u[4]; bf16x8 b; } x;
#pragma unroll
  for (int i = 0; i < 4; ++i) x.u[i] = cvtpk(f[2 * i], f[2 * i + 1]);
  return x.b;
}

// Light barrier: drain LDS ops only; global stores stay in flight.
__device__ __forceinline__ void lbar() {
  __builtin_amdgcn_sched_barrier(0);
  asm volatile("s_waitcnt lgkmcnt(0)" ::: "memory");
  __builtin_amdgcn_s_barrier();
  __builtin_amdgcn_sched_barrier(0);
}

// Fused causal SDPA. Each block = 2 complementary 64-row q-tiles (qa=qt,
// qb=63-qt): identical store/MFMA/fill work per block for any scheduling.
// Waves 0-3 own tile A, waves 4-7 tile B. Zero-fill of the upper triangle
// is interleaved into the main loop (3-4 float4 stores/thread/iter) to use
// the idle store BW of the latency-bound loop instead of a serial tail.
__global__ __launch_bounds__(512, 4) void sdpa_fused(
    const float* __restrict__ qg, const float* __restrict__ kg,
    const float* __restrict__ vg, float* __restrict__ outg) {
  const int bid = blockIdx.x;
  const int xcd = bid & 7;
  const int ii = bid >> 3;       // 0..63
  const int hh = ii >> 5;        // head within XCD
  const int qt = ii & 31;
  const int b = 2 * xcd + hh;    // 2 heads per XCD (K+V 4MB ~ L2)
  const int qa = qt, qb = 63 - qt;

  const int tid = threadIdx.x;
  const int w = tid >> 6, lane = tid & 63;
  const int g = lane >> 4, c = lane & 15;
  const int grp = w >> 2;              // 0: tile A, 1: tile B
  const int wr0 = 16 * (w & 3);
  const int qrw = (grp ? qb : qa) * 64;  // this wave's q-tile row base
  const int kmax = grp ? qb : qa;        // last K-tile this wave computes
  const int pOff = 16 * w;               // wave-private Pl rows

  const float* qbp = qg + (size_t)b * NSEQ * DH;
  const float* kbp = kg + (size_t)b * NSEQ * DH;
  const float* vbp = vg + (size_t)b * NSEQ * DH;
  float* outb = outg + (size_t)b * NSEQ * DH;
  float* attnb = outg + (size_t)NBH * NSEQ * DH + (size_t)b * NSEQ * NSEQ;

  __shared__ unsigned short Kl[2][64][72];
  __shared__ unsigned int Vt[2][64][37];   // u32 = {bf16 V[2p][d], bf16 V[2p+1][d]}
  __shared__ unsigned short Pl[128][72];   // wave-private 16-row slabs

  // ---- interleaved zero-fill state (block-uniform walk) ----
  // Fill strict-upper region of tile A then tile B; one step = 4 rows x 64
  // f4-cols (threads: row = 4*band + tid>>6, f4col = colblk*64 + (tid&63)).
  int fTile = 0;
  int fq0 = qa;
  int fzc4 = 16 * (qa + 1);      // first f4-col to fill
  int fblk = fzc4 >> 6;          // qa<=31 -> fblk<=8 <16: tile A never empty
  int fband = 0;
  const int fr = tid >> 6, fc = tid & 63;
  auto fillStep = [&]() {
    if (fTile > 1) return;
    const int r = fq0 * 64 + 4 * fband + fr;
    const int c4 = fblk * 64 + fc;
    if (c4 >= fzc4) {
      const float4 z = {0.f, 0.f, 0.f, 0.f};
      *(float4*)(attnb + (size_t)r * NSEQ + 4 * c4) = z;
    }
    if (++fband == 16) {
      fband = 0;
      if (++fblk == 16) {
        if (fTile == 0) {
          fTile = 1; fq0 = qb; fzc4 = 16 * (qb + 1); fblk = fzc4 >> 6; 
          if (fblk >= 16) fTile = 2;
        } else {
          fTile = 2;
        }
      }
    }
  };
  const int nfs = (qt >= 22) ? 4 : 3;   // steps per loop iteration

  // ---- Q fragments: row = qrw+wr0+c, k = 32ks+8g+e ----
  bf16x8 aq[2];
  {
    const float* qrow = qbp + (size_t)(qrw + wr0 + c) * DH;
#pragma unroll
    for (int ks = 0; ks < 2; ++ks) {
      float f[8];
      *(float4*)f = *(const float4*)(qrow + 32 * ks + 8 * g);
      *(float4*)(f + 4) = *(const float4*)(qrow + 32 * ks + 8 * g + 4);
      aq[ks] = pk8(f);
    }
  }

  // ---- staging maps ----
  const int kj = tid >> 3, kcs = tid & 7;   // K: row kj, 8-float chunk
  const int vp = tid >> 4, dch = tid & 15;  // V: row-pair vp, 4-dim chunk
  float kf[8], vf0[4], vf1[4];

  auto loadK = [&](int kt) {
    const float* s = kbp + (size_t)(kt * 64 + kj) * DH + kcs * 8;
    *(float4*)kf = ((const float4*)s)[0];
    *(float4*)(kf + 4) = ((const float4*)s)[1];
  };
  auto writeK = [&](int cur) {
    u32x4 u;
#pragma unroll
    for (int i = 0; i < 4; ++i) u[i] = cvtpk(kf[2 * i], kf[2 * i + 1]);
    *(u32x4*)&Kl[cur][kj][kcs * 8] = u;
  };
  auto loadV = [&](int kt) {
    const float* s0 = vbp + (size_t)(kt * 64 + 2 * vp) * DH + dch * 4;
    *(float4*)vf0 = *(const float4*)s0;
    *(float4*)vf1 = *(const float4*)(s0 + DH);
  };
  auto writeV = [&](int cur) {
#pragma unroll
    for (int e = 0; e < 4; ++e) Vt[cur][4 * dch + e][vp] = cvtpk(vf0[e], vf1[e]);
  };

  // ================= pass 1: l = sum(exp(s)) =================
  float part[4] = {0.f, 0.f, 0.f, 0.f};
  loadK(0);
  for (int kt = 0; kt <= qb; ++kt) {
    const int cur = kt & 1;
    writeK(cur);
    lbar();
    if (kt < qb) loadK(kt + 1);
    if (kt <= kmax) {
      f32x4 acc[4];
#pragma unroll
      for (int ct = 0; ct < 4; ++ct) acc[ct] = (f32x4){0.f, 0.f, 0.f, 0.f};
      __builtin_amdgcn_s_setprio(1);
#pragma unroll
      for (int ks = 0; ks < 2; ++ks)
#pragma unroll
        for (int ct = 0; ct < 4; ++ct) {
          u16x8 u = *(const u16x8*)&Kl[cur][16 * ct + c][32 * ks + 8 * g];
          acc[ct] = __builtin_amdgcn_mfma_f32_16x16x32_bf16(aq[ks], __builtin_bit_cast(bf16x8, u), acc[ct], 0, 0, 0);
        }
      __builtin_amdgcn_s_setprio(0);
#pragma unroll
      for (int ct = 0; ct < 4; ++ct)
#pragma unroll
        for (int r = 0; r < 4; ++r) {
          const int j = kt * 64 + 16 * ct + c;
          const int i = qrw + wr0 + 4 * g + r;
          part[r] += (j <= i) ? __expf(acc[ct][r] * 0.125f) : 0.f;
        }
    }
    for (int fs = 0; fs < nfs; ++fs) fillStep();
  }
  float rinv[4];
#pragma unroll
  for (int r = 0; r < 4; ++r) {
    float s = part[r];
    s += __shfl_xor(s, 1); s += __shfl_xor(s, 2);
    s += __shfl_xor(s, 4); s += __shfl_xor(s, 8);
    rinv[r] = 1.f / s;
  }

  __syncthreads();  // full drain between passes (Kl reuse)

  // ================= pass 2: attn + PV =================
  loadK(0);
  loadV(0);
  f32x4 oacc[4];
#pragma unroll
  for (int ct = 0; ct < 4; ++ct) oacc[ct] = (f32x4){0.f, 0.f, 0.f, 0.f};

  for (int kt = 0; kt <= qb; ++kt) {
    const int cur = kt & 1;
    writeK(cur);
    writeV(cur);
    lbar();
    if (kt < qb) { loadK(kt + 1); loadV(kt + 1); }

    if (kt <= kmax) {
      f32x4 acc[4];
#pragma unroll
      for (int ct = 0; ct < 4; ++ct) acc[ct] = (f32x4){0.f, 0.f, 0.f, 0.f};
      __builtin_amdgcn_s_setprio(1);
#pragma unroll
      for (int ks = 0; ks < 2; ++ks)
#pragma unroll
        for (int ct = 0; ct < 4; ++ct) {
          u16x8 u = *(const u16x8*)&Kl[cur][16 * ct + c][32 * ks + 8 * g];
          acc[ct] = __builtin_amdgcn_mfma_f32_16x16x32_bf16(aq[ks], __builtin_bit_cast(bf16x8, u), acc[ct], 0, 0, 0);
        }
      __builtin_amdgcn_s_setprio(0);

#pragma unroll
      for (int ct = 0; ct < 4; ++ct)
#pragma unroll
        for (int r = 0; r < 4; ++r) {
          const int jl = 16 * ct + c;
          const int i = qrw + wr0 + 4 * g + r;
          const int j = kt * 64 + jl;
          const float p = (j <= i) ? __expf(acc[ct][r] * 0.125f) * rinv[r] : 0.f;
          Pl[pOff + 4 * g + r][jl] = (unsigned short)cvtpk(p, p);
          attnb[(size_t)i * NSEQ + j] = p;  // stays in flight across lbar
        }

      // wave-synchronous transpose read of own Pl slab
      bf16x8 ap[2];
#pragma unroll
      for (int ks = 0; ks < 2; ++ks)
        ap[ks] = __builtin_bit_cast(bf16x8, *(const u16x8*)&Pl[pOff + c][32 * ks + 8 * g]);
      __builtin_amdgcn_s_setprio(1);
#pragma unroll
      for (int ks = 0; ks < 2; ++ks)
#pragma unroll
        for (int ct = 0; ct < 4; ++ct) {
          u16x8 bv = *(const u16x8*)&Vt[cur][16 * ct + c][16 * ks + 4 * g];
          oacc[ct] = __builtin_amdgcn_mfma_f32_16x16x32_bf16(ap[ks], __builtin_bit_cast(bf16x8, bv), oacc[ct], 0, 0, 0);
        }
      __builtin_amdgcn_s_setprio(0);
    }
    for (int fs = 0; fs < nfs; ++fs) fillStep();
  }

  // ---- out write ----
#pragma unroll
  for (int ct = 0; ct < 4; ++ct)
#pragma unroll
    for (int r = 0; r < 4; ++r) {
      const int i = qrw + wr0 + 4 * g + r;
      outb[(size_t)i * DH + 16 * ct + c] = oacc[ct][r];
    }

  // ---- finish any remaining fill steps ----
  while (fTile < 2) fillStep();
}

extern "C" void kernel_launch(void* const* d_in, const int* in_sizes, int n_in,
                              void* d_out, int out_size, void* d_ws, size_t ws_size,
                              hipStream_t stream) {
  (void)in_sizes; (void)n_in; (void)out_size; (void)d_ws; (void)ws_size;
  const float* q = (const float*)d_in[0];
  const float* k = (const float*)d_in[1];
  const float* v = (const float*)d_in[2];
  float* out = (float*)d_out;
  sdpa_fused<<<dim3(512), dim3(512), 0, stream>>>(q, k, v, out);
}